// Round 9
// baseline (361.425 us; speedup 1.0000x reference)
//
#include <hip/hip_runtime.h>

// B=8 S=1024 D=1024 H=16 DH=64.
// Head bh=b*16+s_hi (s_hi=s>>6); head elem (p,f) -> proj[b][s_hi*64+(p>>4)][(p&15)*64+f].
// mask index for head bh is s_hi&7. scale=0.5 (=> exp2 domain: 0.5*log2e).

typedef unsigned short u16;
typedef unsigned long long u64;
typedef __attribute__((ext_vector_type(8))) short bf16x8;
typedef __attribute__((ext_vector_type(4))) float f32x4;

#define MFMA_BF16(a, b, c) __builtin_amdgcn_mfma_f32_16x16x32_bf16((a), (b), (c), 0, 0, 0)

__device__ __forceinline__ u16 f2bf(float f) {
  unsigned u = __float_as_uint(f);
  u += 0x7fffu + ((u >> 16) & 1u);   // round-nearest-even
  return (u16)(u >> 16);
}
__device__ __forceinline__ float bf2f(u16 b) {
  return __uint_as_float(((unsigned)b) << 16);
}
__device__ __forceinline__ unsigned cvt_pk_bf16(float lo, float hi) {
  unsigned r;
  asm("v_cvt_pk_bf16_f32 %0, %1, %2" : "=v"(r) : "v"(lo), "v"(hi));
  return r;
}
__device__ __forceinline__ void gload_lds16(const u16* g, u16* l) {
  __builtin_amdgcn_global_load_lds(
      (const __attribute__((address_space(1))) void*)g,
      (__attribute__((address_space(3))) void*)l, 16, 0, 0);
}

static constexpr size_t MD = 8192ull * 1024ull;  // one [B,S,D] tensor, elements
static constexpr size_t DD = 1024ull * 1024ull;  // one [D,D] weight, elements
static constexpr float SCL = 0.72134752044f;     // 0.5 * log2(e)

// ------- fused W-transpose (z=0..3) + mask bitpack (z=4) -------
// wt: W[K,N] f32 -> WT[N,K] bf16. mb: mask -> mb[8][1024][16] u64 bitwords.
__global__ __launch_bounds__(256) void wtmb_k(
    const float* __restrict__ Wk, const float* __restrict__ Wv,
    const float* __restrict__ Wq, const float* __restrict__ Wf,
    const unsigned char* __restrict__ mask8, u16* __restrict__ WT,
    u64* __restrict__ mb) {
  __shared__ float tile[32][33];
  __shared__ int mflag;
  const int z = blockIdx.z;
  const int t = threadIdx.x;
  if (z < 4) {
    const float* W = (z == 0) ? Wk : ((z == 1) ? Wv : ((z == 2) ? Wq : Wf));
    const int k0 = blockIdx.y * 32, n0 = blockIdx.x * 32;
    const int r = t >> 5, c = t & 31;
#pragma unroll
    for (int rr = r; rr < 32; rr += 8)
      tile[rr][c] = W[(size_t)(k0 + rr) * 1024 + n0 + c];
    __syncthreads();
#pragma unroll
    for (int rr = r; rr < 32; rr += 8)
      WT[(size_t)z * DD + (size_t)(n0 + rr) * 1024 + k0 + c] = f2bf(tile[c][rr]);
    return;
  }
  // ---- mask bitpack: block id covers 128 words (threads 0..127) ----
  if (t == 0) {
    const unsigned* mw = reinterpret_cast<const unsigned*>(mask8);
    int allW = 1;  // storage is 4-byte words (int32 0/1 or f32 0.0/1.0)?
    for (int i = 0; i < 64; ++i) {
      const unsigned v = mw[i];
      if (v != 0u && v != 1u && v != 0x3F800000u) allW = 0;
    }
    mflag = allW;
  }
  __syncthreads();
  if (t >= 128) return;
  const int wide = mflag;
  const size_t wi = (size_t)(blockIdx.y * 32 + blockIdx.x) * 128 + t;  // word idx
  const size_t src0 = wi * 64;
  u64 bits = 0ull;
  if (!wide) {  // u8 bool storage
    const uint4* p = reinterpret_cast<const uint4*>(mask8 + src0);
#pragma unroll
    for (int q = 0; q < 4; ++q) {
      const uint4 v = p[q];
      const unsigned vv[4] = {v.x, v.y, v.z, v.w};
#pragma unroll
      for (int k = 0; k < 4; ++k) {
        unsigned tt = vv[k];
        tt |= tt >> 4; tt |= tt >> 2; tt |= tt >> 1;
        tt &= 0x01010101u;
        const unsigned nib =
            (tt & 1u) | ((tt >> 7) & 2u) | ((tt >> 14) & 4u) | ((tt >> 21) & 8u);
        bits |= (u64)nib << (q * 16 + k * 4);
      }
    }
  } else {  // 4-byte storage: nonzero word => masked
    const unsigned* p = reinterpret_cast<const unsigned*>(mask8) + src0;
#pragma unroll
    for (int k = 0; k < 64; ++k)
      bits |= (u64)(p[k] != 0u) << k;
  }
  mb[wi] = bits;
}

// ------- projection GEMM: C[z] = X[z](f32) * WT[z]^T + bias -> bf16 -------
// A reg-staged from f32 with in-flight cvt_pk -> padded As[128][40] (conflict-
// free frag reads); B via global_load_lds, linear Bs. m97-style K-loop.
__global__ __launch_bounds__(256) void gemm_proj(
    const float* __restrict__ K0, const float* __restrict__ V0,
    const float* __restrict__ Q0, const u16* __restrict__ B0,
    const float* __restrict__ bias0, const float* __restrict__ bias1,
    const float* __restrict__ bias2, u16* __restrict__ Obf) {
  __shared__ __align__(16) u16 As[128 * 40];  // padded stride 40
  __shared__ __align__(16) u16 Bs[128 * 32];  // linear (gload_lds dest)
  const int z = blockIdx.z;
  const float* Af = (z == 0) ? K0 : ((z == 1) ? V0 : Q0);
  const u16* Bt = B0 + (size_t)z * DD;
  const float* bias = (z == 0) ? bias0 : ((z == 1) ? bias1 : bias2);
  const int t = threadIdx.x;
  const int m0 = blockIdx.y * 128, n0 = blockIdx.x * 128;
  const int w = t >> 6, lane = t & 63, lr = lane & 15, lk = lane >> 4;
  const int wm = (w >> 1) * 64, wn = (w & 1) * 64;
  const int srow = lane >> 2, scol = (lane & 3) * 8;  // B-staging, 16-row chunk
  const int arow = t >> 3, acol = (t & 7) * 4;        // A-staging: 32 rows/pass

  f32x4 acc[4][4] = {};

  for (int k0 = 0; k0 < 1024; k0 += 32) {
    // A loads issued before barrier -> overlap previous iter's MFMAs
    float4 av[4];
#pragma unroll
    for (int p = 0; p < 4; ++p)
      av[p] = *reinterpret_cast<const float4*>(
          Af + (size_t)(m0 + p * 32 + arow) * 1024 + k0 + acol);
    __syncthreads();  // previous iter's fragment reads done before overwrite
#pragma unroll
    for (int it = 0; it < 2; ++it) {
      const int c = w * 2 + it;  // chunk = 16 rows; wave-uniform LDS base
      gload_lds16(Bt + (size_t)(n0 + 16 * c + srow) * 1024 + k0 + scol,
                  &Bs[c * 512 + lane * 8]);
    }
#pragma unroll
    for (int p = 0; p < 4; ++p) {
      const unsigned lo = cvt_pk_bf16(av[p].x, av[p].y);
      const unsigned hi = cvt_pk_bf16(av[p].z, av[p].w);
      *reinterpret_cast<u64*>(&As[(p * 32 + arow) * 40 + acol]) =
          (u64)lo | ((u64)hi << 32);
    }
    __syncthreads();  // staging visible (barrier drains vmcnt+lgkmcnt)
    bf16x8 af[4], bfr[4];
#pragma unroll
    for (int i = 0; i < 4; ++i)
      af[i] = *reinterpret_cast<const bf16x8*>(&As[(wm + i * 16 + lr) * 40 + lk * 8]);
#pragma unroll
    for (int j = 0; j < 4; ++j)
      bfr[j] = *reinterpret_cast<const bf16x8*>(&Bs[(wn + j * 16 + lr) * 32 + lk * 8]);
#pragma unroll
    for (int i = 0; i < 4; ++i) {
#pragma unroll
      for (int j = 0; j < 4; ++j)
        acc[i][j] = MFMA_BF16(af[i], bfr[j], acc[i][j]);
    }
  }

#pragma unroll
  for (int i = 0; i < 4; ++i) {
#pragma unroll
    for (int j = 0; j < 4; ++j) {
#pragma unroll
      for (int r = 0; r < 4; ++r) {
        const int row = m0 + wm + i * 16 + lk * 4 + r;  // C/D: row=(lane>>4)*4+reg
        const int col = n0 + wn + j * 16 + lr;          //       col=lane&15
        Obf[(size_t)z * MD + (size_t)row * 1024 + col] =
            f2bf(acc[i][j][r] + bias[col]);
      }
    }
  }
}

// ------- final GEMM: C = CTX * Wf^T + bias + resid -> bf16 (preLN) -------
__global__ __launch_bounds__(256) void gemm_fin(
    const u16* __restrict__ A, const u16* __restrict__ Bt,
    const float* __restrict__ bias, u16* __restrict__ Obf,
    const float* __restrict__ resid) {
  __shared__ __align__(16) u16 As[128 * 32];
  __shared__ __align__(16) u16 Bs[128 * 32];
  const int t = threadIdx.x;
  const int m0 = blockIdx.y * 128, n0 = blockIdx.x * 128;
  const int w = t >> 6, lane = t & 63, lr = lane & 15, lk = lane >> 4;
  const int wm = (w >> 1) * 64, wn = (w & 1) * 64;
  const int srow = lane >> 2, scol = (lane & 3) * 8;

  f32x4 acc[4][4] = {};

  for (int k0 = 0; k0 < 1024; k0 += 32) {
    __syncthreads();
#pragma unroll
    for (int it = 0; it < 2; ++it) {
      const int c = w * 2 + it;
      gload_lds16(A + (size_t)(m0 + 16 * c + srow) * 1024 + k0 + scol,
                  &As[c * 512 + lane * 8]);
      gload_lds16(Bt + (size_t)(n0 + 16 * c + srow) * 1024 + k0 + scol,
                  &Bs[c * 512 + lane * 8]);
    }
    __syncthreads();
    bf16x8 af[4], bfr[4];
#pragma unroll
    for (int i = 0; i < 4; ++i)
      af[i] = *reinterpret_cast<const bf16x8*>(&As[(wm + i * 16 + lr) * 32 + lk * 8]);
#pragma unroll
    for (int j = 0; j < 4; ++j)
      bfr[j] = *reinterpret_cast<const bf16x8*>(&Bs[(wn + j * 16 + lr) * 32 + lk * 8]);
#pragma unroll
    for (int i = 0; i < 4; ++i) {
#pragma unroll
      for (int j = 0; j < 4; ++j)
        acc[i][j] = MFMA_BF16(af[i], bfr[j], acc[i][j]);
    }
  }

#pragma unroll
  for (int i = 0; i < 4; ++i) {
#pragma unroll
    for (int j = 0; j < 4; ++j) {
#pragma unroll
      for (int r = 0; r < 4; ++r) {
        const int row = m0 + wm + i * 16 + lk * 4 + r;
        const int col = n0 + wn + j * 16 + lr;
        const size_t idx = (size_t)row * 1024 + col;
        Obf[idx] = f2bf(acc[i][j][r] + bias[col] + resid[idx]);
      }
    }
  }
}

// ---------------- V head-transpose: Vt[bh][f][p'] bf16 ----------------
__global__ __launch_bounds__(256) void vt_k(const u16* __restrict__ VP,
                                            u16* __restrict__ VTo) {
  __shared__ __align__(16) u16 tile[64][72];
  const int t = threadIdx.x;
  const int bh = blockIdx.y, p0 = blockIdx.x * 64;
  const int b = bh >> 4, shi = bh & 15;
  const size_t hb = (size_t)b * 1048576 + (size_t)shi * 65536;
#pragma unroll
  for (int it = 0; it < 2; ++it) {
    const int c = t + it * 256;
    const int row = c >> 3, f8 = (c & 7) * 8;
    const int p = p0 + row;
    *reinterpret_cast<int4*>(&tile[row][f8]) = *reinterpret_cast<const int4*>(
        VP + hb + (size_t)(p >> 4) * 1024 + (p & 15) * 64 + f8);
  }
  __syncthreads();
#pragma unroll
  for (int it = 0; it < 2; ++it) {
    const int c = t + it * 256;
    const int f = c >> 3, pc = (c & 7) * 8;
    __align__(16) u16 tmp[8];
#pragma unroll
    for (int i = 0; i < 8; ++i) tmp[i] = tile[pc + i][f];
    *reinterpret_cast<int4*>(VTo + (size_t)bh * 65536 + (size_t)f * 1024 + p0 + pc) =
        *reinterpret_cast<int4*>(tmp);
  }
}

// ---------------- fused attention, single-pass, wave-specialized tail --------
// Grid (32, 128): qt = blockIdx.x FAST (L2 working set ~2 heads/XCD), bh = .y.
// 512 threads (8 waves), 2 blocks/CU. Block = 32 q-rows.
__global__ __launch_bounds__(512, 4) void attn_k(
    const u16* __restrict__ QP, const u16* __restrict__ KP,
    const u16* __restrict__ VT, const u64* __restrict__ mb,
    float* __restrict__ attnOut, u16* __restrict__ ctx) {
  __shared__ __align__(16) u16 Ps[32 * 1024];   // 64 KiB; swizzled
  __shared__ float red[8][2][16];

  const int t = threadIdx.x;
  const int qt = blockIdx.x;
  const int bh = blockIdx.y;
  const int q0 = qt * 32;
  const int b = bh >> 4, shi = bh & 15;
  const size_t hb = (size_t)b * 1048576 + (size_t)shi * 65536;
  const u64* mrow = mb + (size_t)(shi & 7) * 16384;  // [1024][16] words

  const int w = t >> 6, lane = t & 63, lr = lane & 15, lk = lane >> 4;
  const int qsw = (lr & 7) << 3;  // swizzle term (q-row low bits = lr&7)

  bf16x8 qf[2][2];
#pragma unroll
  for (int rg = 0; rg < 2; ++rg) {
    const u16* qb = QP + hb + (size_t)(qt * 2 + rg) * 1024 + lr * 64 + lk * 8;
    qf[rg][0] = *reinterpret_cast<const bf16x8*>(qb);
    qf[rg][1] = *reinterpret_cast<const bf16x8*>(qb + 32);
  }

  float psum[2] = {0.f, 0.f};

  // ---- phase 1: wave w handles kt = 2w, 2w+1 ----
#pragma unroll
  for (int ki = 0; ki < 2; ++ki) {
    const int kt = w * 2 + ki;
    const u16* kb = KP + hb + (size_t)(kt * 4) * 1024 + lr * 64 + lk * 8;
    bf16x8 kf[4][2];
#pragma unroll
    for (int j = 0; j < 4; ++j) {
      kf[j][0] = *reinterpret_cast<const bf16x8*>(kb + j * 1024);
      kf[j][1] = *reinterpret_cast<const bf16x8*>(kb + j * 1024 + 32);
    }
#pragma unroll
    for (int rg = 0; rg < 2; ++rg) {
      f32x4 sf[4];
#pragma unroll
      for (int j = 0; j < 4; ++j) {
        f32x4 a = {};
        a = MFMA_BF16(kf[j][0], qf[rg][0], a);
        a = MFMA_BF16(kf[j][1], qf[rg][1], a);
        sf[j] = a;  // S[k = kt*64+j*16+lk*4+r][q-row rg*16+lr]
      }
      const u64 mw = mrow[(size_t)(q0 + rg * 16 + lr) * 16 + kt];
#pragma unroll
      for (int j = 0; j < 4; ++j) {
        float p[4];
#pragma unroll
        for (int r = 0; r < 4; ++r) {
          const unsigned bit = (unsigned)(mw >> (j * 16 + lk * 4 + r)) & 1u;
          const float sel = bit ? -__builtin_inff() : 0.0f;
          p[r] = __builtin_amdgcn_exp2f(fmaf(sf[j][r], SCL, sel));
          psum[rg] += p[r];
        }
        const unsigned lo = cvt_pk_bf16(p[0], p[1]);
        const unsigned hi = cvt_pk_bf16(p[2], p[3]);
        const int kel = (kt * 64 + j * 16 + lk * 4) ^ qsw;
        *reinterpret_cast<u64*>(&Ps[(rg * 16 + lr) * 1024 + kel]) =
            (u64)lo | ((u64)hi << 32);
      }
    }
  }
#pragma unroll
  for (int rg = 0; rg < 2; ++rg) {
    psum[rg] += __shfl_xor(psum[rg], 16, 64);
    psum[rg] += __shfl_xor(psum[rg], 32, 64);
  }
  if (lane < 16) { red[w][0][lr] = psum[0]; red[w][1][lr] = psum[1]; }
  __syncthreads();

  // per-lane rinv for rows 0..31, shfl-broadcast
  float rsl = 0.f;
  if (lane < 32) {
#pragma unroll
    for (int w2 = 0; w2 < 8; ++w2) rsl += red[w2][lane >> 4][lane & 15];
  }
  const float rinvl = (rsl > 0.f) ? __builtin_amdgcn_rcpf(rsl) : 0.f;

  if (w < 4) {
    // ---- PV (waves 0-3): wave w -> ctx cols w*16..+15, both row groups ----
    const int cg = w * 16;
    const u16* vb = VT + (size_t)bh * 65536 + (size_t)(cg + lr) * 1024 + lk * 8;
    f32x4 cacc[2][2] = {};
#pragma unroll
    for (int kk = 0; kk < 32; ++kk) {
      const int kel = (kk * 32 + lk * 8) ^ qsw;
      const bf16x8 vf = *reinterpret_cast<const bf16x8*>(vb + kk * 32);
      const bf16x8 pf0 = *reinterpret_cast<const bf16x8*>(&Ps[lr * 1024 + kel]);
      const bf16x8 pf1 = *reinterpret_cast<const bf16x8*>(&Ps[(16 + lr) * 1024 + kel]);
      cacc[0][kk & 1] = MFMA_BF16(pf0, vf, cacc[0][kk & 1]);
      cacc[1][kk & 1] = MFMA_BF16(pf1, vf, cacc[1][kk & 1]);
    }
#pragma unroll
    for (int rg = 0; rg < 2; ++rg) {
#pragma unroll
      for (int r = 0; r < 4; ++r) {
        const int lrow = rg * 16 + lk * 4 + r;
        const float ri = __shfl(rinvl, lrow, 64);
        const float cv = cacc[rg][0][r] + cacc[rg][1][r];
        const int p = q0 + lrow;
        ctx[hb + (size_t)(p >> 4) * 1024 + (size_t)(p & 15) * 64 + cg + lr] =
            f2bf(cv * ri);
      }
    }
  } else {
    // ---- stores (waves 4-7): attnOut row i per iteration, 256 threads ----
    const int t2 = t - 256;
    float* aout = attnOut + (size_t)bh * 1048576 + (size_t)q0 * 1024;
#pragma unroll
    for (int i = 0; i < 32; ++i) {
      const int asw = (i & 7) << 3;
      const float ri = __shfl(rinvl, i, 64);
      const u64 p4 = *reinterpret_cast<const u64*>(&Ps[i * 1024 + ((t2 * 4) ^ asw)]);
      f32x4 o;
      o[0] = bf2f((u16)(p4 & 0xffffu)) * ri;
      o[1] = bf2f((u16)((p4 >> 16) & 0xffffu)) * ri;
      o[2] = bf2f((u16)((p4 >> 32) & 0xffffu)) * ri;
      o[3] = bf2f((u16)(p4 >> 48)) * ri;
      __builtin_nontemporal_store(
          o, reinterpret_cast<f32x4*>(aout + (size_t)i * 1024 + t2 * 4));
    }
  }
}

// ---------------- LayerNorm over last dim (1024), bf16 input ----------------
__global__ __launch_bounds__(256) void ln_k(const u16* __restrict__ X,
                                            const float* __restrict__ gamma,
                                            const float* __restrict__ beta,
                                            float* __restrict__ Y) {
  const int row = blockIdx.x, t = threadIdx.x;
  const size_t base = (size_t)row * 1024;
  const u64 xw = *reinterpret_cast<const u64*>(X + base + t * 4);
  float x0 = bf2f((u16)(xw & 0xffffu));
  float x1 = bf2f((u16)((xw >> 16) & 0xffffu));
  float x2 = bf2f((u16)((xw >> 32) & 0xffffu));
  float x3 = bf2f((u16)(xw >> 48));
  float s = x0 + x1 + x2 + x3;
  float s2 = x0 * x0 + x1 * x1 + x2 * x2 + x3 * x3;
#pragma unroll
  for (int d = 1; d < 64; d <<= 1) {
    s += __shfl_xor(s, d, 64);
    s2 += __shfl_xor(s2, d, 64);
  }
  __shared__ float red[8];
  const int w = t >> 6;
  if ((t & 63) == 0) { red[w] = s; red[4 + w] = s2; }
  __syncthreads();
  s = red[0] + red[1] + red[2] + red[3];
  s2 = red[4] + red[5] + red[6] + red[7];
  const float mu = s * (1.f / 1024.f);
  const float var = s2 * (1.f / 1024.f) - mu * mu;
  const float inv = rsqrtf(var + 1e-5f);
  const float4 g = *reinterpret_cast<const float4*>(gamma + t * 4);
  const float4 be = *reinterpret_cast<const float4*>(beta + t * 4);
  float4 y;
  y.x = (x0 - mu) * inv * g.x + be.x;
  y.y = (x1 - mu) * inv * g.y + be.y;
  y.z = (x2 - mu) * inv * g.z + be.z;
  y.w = (x3 - mu) * inv * g.w + be.w;
  *reinterpret_cast<float4*>(Y + base + t * 4) = y;
}

extern "C" void kernel_launch(void* const* d_in, const int* in_sizes, int n_in,
                              void* d_out, int out_size, void* d_ws, size_t ws_size,
                              hipStream_t stream) {
  const float* keyF = (const float*)d_in[0];
  const float* valueF = (const float*)d_in[1];
  const float* queryF = (const float*)d_in[2];
  const unsigned char* mask8 = (const unsigned char*)d_in[3];
  const float* Wk = (const float*)d_in[4];
  const float* bk = (const float*)d_in[5];
  const float* Wv = (const float*)d_in[6];
  const float* bv = (const float*)d_in[7];
  const float* Wq = (const float*)d_in[8];
  const float* bq = (const float*)d_in[9];
  const float* Wf = (const float*)d_in[10];
  const float* bfp = (const float*)d_in[11];
  const float* gamma = (const float*)d_in[12];
  const float* beta = (const float*)d_in[13];

  char* ws = (char*)d_ws;
  // layout (bytes): [48M,56M) WT x4 | [56M,104M) K/V/Q proj | [104M,120M) Vt |
  // [120M,121M) mask bits. After projections: [0,16M) ctx, [16M,32M) preLN bf16.
  u16* WT = (u16*)(ws + 50331648);
  u16* KP = (u16*)(ws + 58720256);
  u16* VP = (u16*)(ws + 75497472);
  u16* QP = (u16*)(ws + 92274688);
  u16* VT = (u16*)(ws + 109051904);
  u64* MB = (u64*)(ws + 125829120);
  u16* CTX = (u16*)(ws);
  u16* PRELN = (u16*)(ws + 16777216);

  float* outF = (float*)d_out;
  float* attnF = outF + 8388608;

  wtmb_k<<<dim3(32, 32, 5), 256, 0, stream>>>(Wk, Wv, Wq, Wf, mask8, WT, MB);
  gemm_proj<<<dim3(8, 64, 3), 256, 0, stream>>>(keyF, valueF, queryF, WT,
                                                bk, bv, bq, KP);
  vt_k<<<dim3(16, 128), 256, 0, stream>>>(VP, VT);
  attn_k<<<dim3(32, 128), 512, 0, stream>>>(QP, KP, VT, MB, attnF, CTX);
  gemm_fin<<<dim3(8, 64), 256, 0, stream>>>(CTX, WT + 3 * DD, bfp, PRELN, queryF);
  ln_k<<<dim3(8192), 256, 0, stream>>>(PRELN, gamma, beta, outF);
}

// Round 10
// 340.542 us; speedup vs baseline: 1.0613x; 1.0613x over previous
//
#include <hip/hip_runtime.h>

// B=8 S=1024 D=1024 H=16 DH=64.
// Head bh=b*16+s_hi (s_hi=s>>6); head elem (p,f) -> proj[b][s_hi*64+(p>>4)][(p&15)*64+f].
// mask index for head bh is s_hi&7. scale=0.5 (=> exp2 domain: 0.5*log2e).

typedef unsigned short u16;
typedef unsigned long long u64;
typedef __attribute__((ext_vector_type(8))) short bf16x8;
typedef __attribute__((ext_vector_type(4))) float f32x4;

#define MFMA_BF16(a, b, c) __builtin_amdgcn_mfma_f32_16x16x32_bf16((a), (b), (c), 0, 0, 0)

__device__ __forceinline__ u16 f2bf(float f) {
  unsigned u = __float_as_uint(f);
  u += 0x7fffu + ((u >> 16) & 1u);   // round-nearest-even
  return (u16)(u >> 16);
}
__device__ __forceinline__ float bf2f(u16 b) {
  return __uint_as_float(((unsigned)b) << 16);
}
__device__ __forceinline__ unsigned cvt_pk_bf16(float lo, float hi) {
  unsigned r;
  asm("v_cvt_pk_bf16_f32 %0, %1, %2" : "=v"(r) : "v"(lo), "v"(hi));
  return r;
}
__device__ __forceinline__ void gload_lds16(const u16* g, u16* l) {
  __builtin_amdgcn_global_load_lds(
      (const __attribute__((address_space(1))) void*)g,
      (__attribute__((address_space(3))) void*)l, 16, 0, 0);
}

static constexpr size_t MD = 8192ull * 1024ull;  // one [B,S,D] tensor, elements
static constexpr size_t DD = 1024ull * 1024ull;  // one [D,D] weight, elements
static constexpr float SCL = 0.72134752044f;     // 0.5 * log2(e)

// ---------------- f32 -> bf16 for key/value/query ----------------
__global__ __launch_bounds__(256) void cvt_k(const float* __restrict__ K,
                                             const float* __restrict__ V,
                                             const float* __restrict__ Q,
                                             u16* __restrict__ O) {
  const int z = blockIdx.z;
  const float* src = (z == 0) ? K : ((z == 1) ? V : Q);
  const size_t i = ((size_t)blockIdx.x * 256 + threadIdx.x) * 4;
  const float4 v = *reinterpret_cast<const float4*>(src + i);
  const unsigned lo = cvt_pk_bf16(v.x, v.y);
  const unsigned hi = cvt_pk_bf16(v.z, v.w);
  *reinterpret_cast<u64*>(O + (size_t)z * MD + i) = (u64)lo | ((u64)hi << 32);
}

// ------- fused W-transpose (z=0..3) + mask bitpack (z=4) -------
// wt: W[K,N] f32 -> WT[N,K] bf16. mb: mask -> mb[8][1024][16] u64 bitwords.
__global__ __launch_bounds__(256) void wtmb_k(
    const float* __restrict__ Wk, const float* __restrict__ Wv,
    const float* __restrict__ Wq, const float* __restrict__ Wf,
    const unsigned char* __restrict__ mask8, u16* __restrict__ WT,
    u64* __restrict__ mb) {
  __shared__ float tile[32][33];
  __shared__ int mflag;
  const int z = blockIdx.z;
  const int t = threadIdx.x;
  if (z < 4) {
    const float* W = (z == 0) ? Wk : ((z == 1) ? Wv : ((z == 2) ? Wq : Wf));
    const int k0 = blockIdx.y * 32, n0 = blockIdx.x * 32;
    const int r = t >> 5, c = t & 31;
#pragma unroll
    for (int rr = r; rr < 32; rr += 8)
      tile[rr][c] = W[(size_t)(k0 + rr) * 1024 + n0 + c];
    __syncthreads();
#pragma unroll
    for (int rr = r; rr < 32; rr += 8)
      WT[(size_t)z * DD + (size_t)(n0 + rr) * 1024 + k0 + c] = f2bf(tile[c][rr]);
    return;
  }
  // ---- mask bitpack: block covers 128 words (threads 0..127) ----
  if (t == 0) {
    const unsigned* mw = reinterpret_cast<const unsigned*>(mask8);
    int allW = 1;  // storage is 4-byte words (int32 0/1 or f32 0.0/1.0)?
    for (int i = 0; i < 64; ++i) {
      const unsigned v = mw[i];
      if (v != 0u && v != 1u && v != 0x3F800000u) allW = 0;
    }
    mflag = allW;
  }
  __syncthreads();
  if (t >= 128) return;
  const int wide = mflag;
  const size_t wi = (size_t)(blockIdx.y * 32 + blockIdx.x) * 128 + t;  // word idx
  const size_t src0 = wi * 64;
  u64 bits = 0ull;
  if (!wide) {  // u8 bool storage
    const uint4* p = reinterpret_cast<const uint4*>(mask8 + src0);
#pragma unroll
    for (int q = 0; q < 4; ++q) {
      const uint4 v = p[q];
      const unsigned vv[4] = {v.x, v.y, v.z, v.w};
#pragma unroll
      for (int k = 0; k < 4; ++k) {
        unsigned tt = vv[k];
        tt |= tt >> 4; tt |= tt >> 2; tt |= tt >> 1;
        tt &= 0x01010101u;
        const unsigned nib =
            (tt & 1u) | ((tt >> 7) & 2u) | ((tt >> 14) & 4u) | ((tt >> 21) & 8u);
        bits |= (u64)nib << (q * 16 + k * 4);
      }
    }
  } else {  // 4-byte storage: nonzero word => masked
    const unsigned* p = reinterpret_cast<const unsigned*>(mask8) + src0;
#pragma unroll
    for (int k = 0; k < 64; ++k)
      bits |= (u64)(p[k] != 0u) << k;
  }
  mb[wi] = bits;
}

// ---------------- GEMM (m97 pattern): C = A * BT^T (+bias, epilogues) -------
// Linear LDS [128][32], global_load_lds width-16, ds_read_b128 fragments.
// EPI==0: C -> bf16 (projections, z=0,1,2). EPI==1: C+resid -> bf16 (preLN).
template <int EPI>
__global__ __launch_bounds__(256) void gemm_bt(
    const u16* __restrict__ A0, const u16* __restrict__ B0,
    const float* __restrict__ bias0, const float* __restrict__ bias1,
    const float* __restrict__ bias2, u16* __restrict__ Obf,
    const float* __restrict__ resid) {
  __shared__ __align__(16) u16 As[128 * 32];  // 64B per row, linear (gload_lds dest)
  __shared__ __align__(16) u16 Bs[128 * 32];
  const int z = blockIdx.z;
  const u16* A = A0 + (size_t)z * MD;
  const u16* Bt = B0 + (size_t)z * DD;
  const float* bias = (z == 0) ? bias0 : ((z == 1) ? bias1 : bias2);
  const int t = threadIdx.x;
  const int m0 = blockIdx.y * 128, n0 = blockIdx.x * 128;
  const int w = t >> 6, lane = t & 63, lr = lane & 15, lk = lane >> 4;
  const int wm = (w >> 1) * 64, wn = (w & 1) * 64;
  const int srow = lane >> 2, scol = (lane & 3) * 8;  // within 16-row chunk

  f32x4 acc[4][4] = {};

  for (int k0 = 0; k0 < 1024; k0 += 32) {
    __syncthreads();  // previous iter's fragment reads done before overwrite
#pragma unroll
    for (int it = 0; it < 2; ++it) {
      const int c = w * 2 + it;  // chunk = 16 rows; wave-uniform LDS base
      gload_lds16(A + (size_t)(m0 + 16 * c + srow) * 1024 + k0 + scol,
                  &As[c * 512 + lane * 8]);
      gload_lds16(Bt + (size_t)(n0 + 16 * c + srow) * 1024 + k0 + scol,
                  &Bs[c * 512 + lane * 8]);
    }
    __syncthreads();  // barrier drain waits vmcnt(0): LDS tiles ready
    bf16x8 af[4], bfr[4];
#pragma unroll
    for (int i = 0; i < 4; ++i)
      af[i] = *reinterpret_cast<const bf16x8*>(&As[(wm + i * 16 + lr) * 32 + lk * 8]);
#pragma unroll
    for (int j = 0; j < 4; ++j)
      bfr[j] = *reinterpret_cast<const bf16x8*>(&Bs[(wn + j * 16 + lr) * 32 + lk * 8]);
#pragma unroll
    for (int i = 0; i < 4; ++i) {
#pragma unroll
      for (int j = 0; j < 4; ++j)
        acc[i][j] = MFMA_BF16(af[i], bfr[j], acc[i][j]);
    }
  }

#pragma unroll
  for (int i = 0; i < 4; ++i) {
#pragma unroll
    for (int j = 0; j < 4; ++j) {
#pragma unroll
      for (int r = 0; r < 4; ++r) {
        const int row = m0 + wm + i * 16 + lk * 4 + r;  // C/D: row=(lane>>4)*4+reg
        const int col = n0 + wn + j * 16 + lr;          //       col=lane&15
        const size_t idx = (size_t)row * 1024 + col;
        const float v = acc[i][j][r] + bias[col];
        if constexpr (EPI == 0) {
          Obf[(size_t)z * MD + idx] = f2bf(v);
        } else {
          Obf[idx] = f2bf(v + resid[idx]);
        }
      }
    }
  }
}

// ---------------- V head-transpose: Vt[bh][f][p'] bf16 ----------------
__global__ __launch_bounds__(256) void vt_k(const u16* __restrict__ VP,
                                            u16* __restrict__ VTo) {
  __shared__ __align__(16) u16 tile[64][72];
  const int t = threadIdx.x;
  const int bh = blockIdx.y, p0 = blockIdx.x * 64;
  const int b = bh >> 4, shi = bh & 15;
  const size_t hb = (size_t)b * 1048576 + (size_t)shi * 65536;
#pragma unroll
  for (int it = 0; it < 2; ++it) {
    const int c = t + it * 256;
    const int row = c >> 3, f8 = (c & 7) * 8;
    const int p = p0 + row;
    *reinterpret_cast<int4*>(&tile[row][f8]) = *reinterpret_cast<const int4*>(
        VP + hb + (size_t)(p >> 4) * 1024 + (p & 15) * 64 + f8);
  }
  __syncthreads();
#pragma unroll
  for (int it = 0; it < 2; ++it) {
    const int c = t + it * 256;
    const int f = c >> 3, pc = (c & 7) * 8;
    __align__(16) u16 tmp[8];
#pragma unroll
    for (int i = 0; i < 8; ++i) tmp[i] = tile[pc + i][f];
    *reinterpret_cast<int4*>(VTo + (size_t)bh * 65536 + (size_t)f * 1024 + p0 + pc) =
        *reinterpret_cast<int4*>(tmp);
  }
}

// ---------------- fused attention, single-pass, wave-specialized tail --------
// Grid (32, 128): qt = blockIdx.x FAST (L2 working set ~2 heads/XCD), bh = .y.
// 512 threads (8 waves), 2 blocks/CU. Block = 32 q-rows.
__global__ __launch_bounds__(512, 4) void attn_k(
    const u16* __restrict__ QP, const u16* __restrict__ KP,
    const u16* __restrict__ VT, const u64* __restrict__ mb,
    float* __restrict__ attnOut, u16* __restrict__ ctx) {
  __shared__ __align__(16) u16 Ps[32 * 1024];   // 64 KiB; swizzled
  __shared__ float red[8][2][16];

  const int t = threadIdx.x;
  const int qt = blockIdx.x;
  const int bh = blockIdx.y;
  const int q0 = qt * 32;
  const int b = bh >> 4, shi = bh & 15;
  const size_t hb = (size_t)b * 1048576 + (size_t)shi * 65536;
  const u64* mrow = mb + (size_t)(shi & 7) * 16384;  // [1024][16] words

  const int w = t >> 6, lane = t & 63, lr = lane & 15, lk = lane >> 4;
  const int qsw = (lr & 7) << 3;  // swizzle term (q-row low bits = lr&7)

  bf16x8 qf[2][2];
#pragma unroll
  for (int rg = 0; rg < 2; ++rg) {
    const u16* qb = QP + hb + (size_t)(qt * 2 + rg) * 1024 + lr * 64 + lk * 8;
    qf[rg][0] = *reinterpret_cast<const bf16x8*>(qb);
    qf[rg][1] = *reinterpret_cast<const bf16x8*>(qb + 32);
  }

  float psum[2] = {0.f, 0.f};

  // ---- phase 1: wave w handles kt = 2w, 2w+1 ----
#pragma unroll
  for (int ki = 0; ki < 2; ++ki) {
    const int kt = w * 2 + ki;
    const u16* kb = KP + hb + (size_t)(kt * 4) * 1024 + lr * 64 + lk * 8;
    bf16x8 kf[4][2];
#pragma unroll
    for (int j = 0; j < 4; ++j) {
      kf[j][0] = *reinterpret_cast<const bf16x8*>(kb + j * 1024);
      kf[j][1] = *reinterpret_cast<const bf16x8*>(kb + j * 1024 + 32);
    }
#pragma unroll
    for (int rg = 0; rg < 2; ++rg) {
      f32x4 sf[4];
#pragma unroll
      for (int j = 0; j < 4; ++j) {
        f32x4 a = {};
        a = MFMA_BF16(kf[j][0], qf[rg][0], a);
        a = MFMA_BF16(kf[j][1], qf[rg][1], a);
        sf[j] = a;  // S[k = kt*64+j*16+lk*4+r][q-row rg*16+lr]
      }
      const u64 mw = mrow[(size_t)(q0 + rg * 16 + lr) * 16 + kt];
#pragma unroll
      for (int j = 0; j < 4; ++j) {
        float p[4];
#pragma unroll
        for (int r = 0; r < 4; ++r) {
          const unsigned bit = (unsigned)(mw >> (j * 16 + lk * 4 + r)) & 1u;
          const float sel = bit ? -__builtin_inff() : 0.0f;
          p[r] = __builtin_amdgcn_exp2f(fmaf(sf[j][r], SCL, sel));
          psum[rg] += p[r];
        }
        const unsigned lo = cvt_pk_bf16(p[0], p[1]);
        const unsigned hi = cvt_pk_bf16(p[2], p[3]);
        const int kel = (kt * 64 + j * 16 + lk * 4) ^ qsw;
        *reinterpret_cast<u64*>(&Ps[(rg * 16 + lr) * 1024 + kel]) =
            (u64)lo | ((u64)hi << 32);
      }
    }
  }
#pragma unroll
  for (int rg = 0; rg < 2; ++rg) {
    psum[rg] += __shfl_xor(psum[rg], 16, 64);
    psum[rg] += __shfl_xor(psum[rg], 32, 64);
  }
  if (lane < 16) { red[w][0][lr] = psum[0]; red[w][1][lr] = psum[1]; }
  __syncthreads();

  // per-lane rinv for rows 0..31, shfl-broadcast
  float rsl = 0.f;
  if (lane < 32) {
#pragma unroll
    for (int w2 = 0; w2 < 8; ++w2) rsl += red[w2][lane >> 4][lane & 15];
  }
  const float rinvl = (rsl > 0.f) ? __builtin_amdgcn_rcpf(rsl) : 0.f;

  if (w < 4) {
    // ---- PV (waves 0-3): wave w -> ctx cols w*16..+15, both row groups ----
    const int cg = w * 16;
    const u16* vb = VT + (size_t)bh * 65536 + (size_t)(cg + lr) * 1024 + lk * 8;
    f32x4 cacc[2][2] = {};
#pragma unroll
    for (int kk = 0; kk < 32; ++kk) {
      const int kel = (kk * 32 + lk * 8) ^ qsw;
      const bf16x8 vf = *reinterpret_cast<const bf16x8*>(vb + kk * 32);
      const bf16x8 pf0 = *reinterpret_cast<const bf16x8*>(&Ps[lr * 1024 + kel]);
      const bf16x8 pf1 = *reinterpret_cast<const bf16x8*>(&Ps[(16 + lr) * 1024 + kel]);
      cacc[0][kk & 1] = MFMA_BF16(pf0, vf, cacc[0][kk & 1]);
      cacc[1][kk & 1] = MFMA_BF16(pf1, vf, cacc[1][kk & 1]);
    }
#pragma unroll
    for (int rg = 0; rg < 2; ++rg) {
#pragma unroll
      for (int r = 0; r < 4; ++r) {
        const int lrow = rg * 16 + lk * 4 + r;
        const float ri = __shfl(rinvl, lrow, 64);
        const float cv = cacc[rg][0][r] + cacc[rg][1][r];
        const int p = q0 + lrow;
        ctx[hb + (size_t)(p >> 4) * 1024 + (size_t)(p & 15) * 64 + cg + lr] =
            f2bf(cv * ri);
      }
    }
  } else {
    // ---- stores (waves 4-7): attnOut row i per iteration, 256 threads ----
    const int t2 = t - 256;
    float* aout = attnOut + (size_t)bh * 1048576 + (size_t)q0 * 1024;
#pragma unroll
    for (int i = 0; i < 32; ++i) {
      const int asw = (i & 7) << 3;
      const float ri = __shfl(rinvl, i, 64);
      const u64 p4 = *reinterpret_cast<const u64*>(&Ps[i * 1024 + ((t2 * 4) ^ asw)]);
      f32x4 o;
      o[0] = bf2f((u16)(p4 & 0xffffu)) * ri;
      o[1] = bf2f((u16)((p4 >> 16) & 0xffffu)) * ri;
      o[2] = bf2f((u16)((p4 >> 32) & 0xffffu)) * ri;
      o[3] = bf2f((u16)(p4 >> 48)) * ri;
      __builtin_nontemporal_store(
          o, reinterpret_cast<f32x4*>(aout + (size_t)i * 1024 + t2 * 4));
    }
  }
}

// ---------------- LayerNorm over last dim (1024), bf16 input ----------------
__global__ __launch_bounds__(256) void ln_k(const u16* __restrict__ X,
                                            const float* __restrict__ gamma,
                                            const float* __restrict__ beta,
                                            float* __restrict__ Y) {
  const int row = blockIdx.x, t = threadIdx.x;
  const size_t base = (size_t)row * 1024;
  const u64 xw = *reinterpret_cast<const u64*>(X + base + t * 4);
  float x0 = bf2f((u16)(xw & 0xffffu));
  float x1 = bf2f((u16)((xw >> 16) & 0xffffu));
  float x2 = bf2f((u16)((xw >> 32) & 0xffffu));
  float x3 = bf2f((u16)(xw >> 48));
  float s = x0 + x1 + x2 + x3;
  float s2 = x0 * x0 + x1 * x1 + x2 * x2 + x3 * x3;
#pragma unroll
  for (int d = 1; d < 64; d <<= 1) {
    s += __shfl_xor(s, d, 64);
    s2 += __shfl_xor(s2, d, 64);
  }
  __shared__ float red[8];
  const int w = t >> 6;
  if ((t & 63) == 0) { red[w] = s; red[4 + w] = s2; }
  __syncthreads();
  s = red[0] + red[1] + red[2] + red[3];
  s2 = red[4] + red[5] + red[6] + red[7];
  const float mu = s * (1.f / 1024.f);
  const float var = s2 * (1.f / 1024.f) - mu * mu;
  const float inv = rsqrtf(var + 1e-5f);
  const float4 g = *reinterpret_cast<const float4*>(gamma + t * 4);
  const float4 be = *reinterpret_cast<const float4*>(beta + t * 4);
  float4 y;
  y.x = (x0 - mu) * inv * g.x + be.x;
  y.y = (x1 - mu) * inv * g.y + be.y;
  y.z = (x2 - mu) * inv * g.z + be.z;
  y.w = (x3 - mu) * inv * g.w + be.w;
  *reinterpret_cast<float4*>(Y + base + t * 4) = y;
}

extern "C" void kernel_launch(void* const* d_in, const int* in_sizes, int n_in,
                              void* d_out, int out_size, void* d_ws, size_t ws_size,
                              hipStream_t stream) {
  const float* keyF = (const float*)d_in[0];
  const float* valueF = (const float*)d_in[1];
  const float* queryF = (const float*)d_in[2];
  const unsigned char* mask8 = (const unsigned char*)d_in[3];
  const float* Wk = (const float*)d_in[4];
  const float* bk = (const float*)d_in[5];
  const float* Wv = (const float*)d_in[6];
  const float* bv = (const float*)d_in[7];
  const float* Wq = (const float*)d_in[8];
  const float* bq = (const float*)d_in[9];
  const float* Wf = (const float*)d_in[10];
  const float* bfp = (const float*)d_in[11];
  const float* gamma = (const float*)d_in[12];
  const float* beta = (const float*)d_in[13];

  char* ws = (char*)d_ws;
  // layout (bytes): [0,48M) Xbf k/v/q bf16 | [48M,56M) WT x4 | [56M,104M) K/V/Q proj
  // | [104M,120M) Vt | [120M,121M) mask bits. After projections: [0,16M) ctx,
  // [16M,32M) preLN bf16 (overwrites Xbf region after its last use).
  u16* Xbf = (u16*)(ws);
  u16* WT = (u16*)(ws + 50331648);
  u16* KP = (u16*)(ws + 58720256);
  u16* VP = (u16*)(ws + 75497472);
  u16* QP = (u16*)(ws + 92274688);
  u16* VT = (u16*)(ws + 109051904);
  u64* MB = (u64*)(ws + 125829120);
  u16* CTX = (u16*)(ws);
  u16* PRELN = (u16*)(ws + 16777216);

  float* outF = (float*)d_out;
  float* attnF = outF + 8388608;

  cvt_k<<<dim3(8192, 1, 3), 256, 0, stream>>>(keyF, valueF, queryF, Xbf);
  wtmb_k<<<dim3(32, 32, 5), 256, 0, stream>>>(Wk, Wv, Wq, Wf, mask8, WT, MB);
  gemm_bt<0><<<dim3(8, 64, 3), 256, 0, stream>>>(Xbf, WT, bk, bv, bq, KP, nullptr);
  vt_k<<<dim3(16, 128), 256, 0, stream>>>(VP, VT);
  attn_k<<<dim3(32, 128), 512, 0, stream>>>(QP, KP, VT, MB, attnF, CTX);
  gemm_bt<1><<<dim3(8, 64, 1), 256, 0, stream>>>(CTX, WT + 3 * DD, bfp, bfp, bfp,
                                                 PRELN, queryF);
  ln_k<<<dim3(8192), 256, 0, stream>>>(PRELN, gamma, beta, outF);
}

// Round 11
// 321.628 us; speedup vs baseline: 1.1237x; 1.0588x over previous
//
#include <hip/hip_runtime.h>

// B=8 S=1024 D=1024 H=16 DH=64.
// Head bh=b*16+s_hi (s_hi=s>>6); head elem (p,f) -> proj[b][s_hi*64+(p>>4)][(p&15)*64+f].
// mask index for head bh is s_hi&7. scale=0.5 (=> exp2 domain: 0.5*log2e).

typedef unsigned short u16;
typedef unsigned long long u64;
typedef __attribute__((ext_vector_type(8))) short bf16x8;
typedef __attribute__((ext_vector_type(4))) float f32x4;

#define MFMA_BF16(a, b, c) __builtin_amdgcn_mfma_f32_16x16x32_bf16((a), (b), (c), 0, 0, 0)

__device__ __forceinline__ u16 f2bf(float f) {
  unsigned u = __float_as_uint(f);
  u += 0x7fffu + ((u >> 16) & 1u);   // round-nearest-even
  return (u16)(u >> 16);
}
__device__ __forceinline__ float bf2f(u16 b) {
  return __uint_as_float(((unsigned)b) << 16);
}
__device__ __forceinline__ unsigned cvt_pk_bf16(float lo, float hi) {
  unsigned r;
  asm("v_cvt_pk_bf16_f32 %0, %1, %2" : "=v"(r) : "v"(lo), "v"(hi));
  return r;
}
__device__ __forceinline__ void gload_lds16(const u16* g, u16* l) {
  __builtin_amdgcn_global_load_lds(
      (const __attribute__((address_space(1))) void*)g,
      (__attribute__((address_space(3))) void*)l, 16, 0, 0);
}

static constexpr size_t MD = 8192ull * 1024ull;  // one [B,S,D] tensor, elements
static constexpr size_t DD = 1024ull * 1024ull;  // one [D,D] weight, elements
static constexpr float SCL = 0.72134752044f;     // 0.5 * log2(e)

// ------- fused f32->bf16 cvt (ids 0..24575) + W-transpose (..28671) + mask ----
// 1D grid, 29696 blocks.
__global__ __launch_bounds__(256) void prep_k(
    const float* __restrict__ K, const float* __restrict__ V,
    const float* __restrict__ Q, const float* __restrict__ Wk,
    const float* __restrict__ Wv, const float* __restrict__ Wq,
    const float* __restrict__ Wf, const unsigned char* __restrict__ mask8,
    u16* __restrict__ O, u16* __restrict__ WT, u64* __restrict__ mb) {
  const int id = blockIdx.x;
  const int t = threadIdx.x;
  if (id < 24576) {  // ---- cvt: 3 x 8192 blocks ----
    const int z = id >> 13, x = id & 8191;
    const float* src = (z == 0) ? K : ((z == 1) ? V : Q);
    const size_t i = ((size_t)x * 256 + t) * 4;
    const float4 v = *reinterpret_cast<const float4*>(src + i);
    const unsigned lo = cvt_pk_bf16(v.x, v.y);
    const unsigned hi = cvt_pk_bf16(v.z, v.w);
    *reinterpret_cast<u64*>(O + (size_t)z * MD + i) = (u64)lo | ((u64)hi << 32);
    return;
  }
  if (id < 28672) {  // ---- W transpose: 4 x 1024 blocks (32x32 tiles) ----
    __shared__ float tile[32][33];
    const int id2 = id - 24576;
    const int z = id2 >> 10, y = (id2 & 1023) >> 5, x = id2 & 31;
    const float* W = (z == 0) ? Wk : ((z == 1) ? Wv : ((z == 2) ? Wq : Wf));
    const int k0 = y * 32, n0 = x * 32;
    const int r = t >> 5, c = t & 31;
#pragma unroll
    for (int rr = r; rr < 32; rr += 8)
      tile[rr][c] = W[(size_t)(k0 + rr) * 1024 + n0 + c];
    __syncthreads();
#pragma unroll
    for (int rr = r; rr < 32; rr += 8)
      WT[(size_t)z * DD + (size_t)(n0 + rr) * 1024 + k0 + c] = f2bf(tile[c][rr]);
    return;
  }
  // ---- mask bitpack: 1024 blocks x 128 words (threads 0..127) ----
  __shared__ int mflag;
  if (t == 0) {
    const unsigned* mw = reinterpret_cast<const unsigned*>(mask8);
    int allW = 1;  // storage is 4-byte words (int32 0/1 or f32 0.0/1.0)?
    for (int i = 0; i < 64; ++i) {
      const unsigned v = mw[i];
      if (v != 0u && v != 1u && v != 0x3F800000u) allW = 0;
    }
    mflag = allW;
  }
  __syncthreads();
  if (t >= 128) return;
  const int wide = mflag;
  const size_t wi = (size_t)(id - 28672) * 128 + t;  // word idx, 131072 total
  const size_t src0 = wi * 64;
  u64 bits = 0ull;
  if (!wide) {  // u8 bool storage
    const uint4* p = reinterpret_cast<const uint4*>(mask8 + src0);
#pragma unroll
    for (int q = 0; q < 4; ++q) {
      const uint4 v = p[q];
      const unsigned vv[4] = {v.x, v.y, v.z, v.w};
#pragma unroll
      for (int k = 0; k < 4; ++k) {
        unsigned tt = vv[k];
        tt |= tt >> 4; tt |= tt >> 2; tt |= tt >> 1;
        tt &= 0x01010101u;
        const unsigned nib =
            (tt & 1u) | ((tt >> 7) & 2u) | ((tt >> 14) & 4u) | ((tt >> 21) & 8u);
        bits |= (u64)nib << (q * 16 + k * 4);
      }
    }
  } else {  // 4-byte storage: nonzero word => masked
    const unsigned* p = reinterpret_cast<const unsigned*>(mask8) + src0;
#pragma unroll
    for (int k = 0; k < 64; ++k)
      bits |= (u64)(p[k] != 0u) << k;
  }
  mb[wi] = bits;
}

// ---------------- GEMM (m97 pattern): C = A * BT^T (+bias, epilogues) -------
// Linear LDS [128][32], global_load_lds width-16, ds_read_b128 fragments.
// XCD-chunk swizzle: consecutive logical blocks (same m-row panel, all n) land
// on ONE XCD -> A panels L2-resident (was 8-XCD scatter = 8x L3 refetch).
// EPI==0: C -> bf16 (projections, z=0,1,2). EPI==1: C+resid -> bf16 (preLN).
template <int EPI>
__global__ __launch_bounds__(256) void gemm_bt(
    const u16* __restrict__ A0, const u16* __restrict__ B0,
    const float* __restrict__ bias0, const float* __restrict__ bias1,
    const float* __restrict__ bias2, u16* __restrict__ Obf,
    const float* __restrict__ resid) {
  __shared__ __align__(16) u16 As[128 * 32];  // 64B per row, linear (gload_lds dest)
  __shared__ __align__(16) u16 Bs[128 * 32];
  // bijective XCD swizzle (nwg % 8 == 0): wg = (flat%8)*cpx + flat/8
  const int nxy = gridDim.x * gridDim.y;
  const int nwg = nxy * gridDim.z;
  const int flat = blockIdx.z * nxy + blockIdx.y * gridDim.x + blockIdx.x;
  const int wg = (flat & 7) * (nwg >> 3) + (flat >> 3);
  const int z = wg / nxy;
  const int rem = wg - z * nxy;
  const int m0 = (rem >> 3) * 128, n0 = (rem & 7) * 128;

  const u16* A = A0 + (size_t)z * MD;
  const u16* Bt = B0 + (size_t)z * DD;
  const float* bias = (z == 0) ? bias0 : ((z == 1) ? bias1 : bias2);
  const int t = threadIdx.x;
  const int w = t >> 6, lane = t & 63, lr = lane & 15, lk = lane >> 4;
  const int wm = (w >> 1) * 64, wn = (w & 1) * 64;
  const int srow = lane >> 2, scol = (lane & 3) * 8;  // within 16-row chunk

  f32x4 acc[4][4] = {};

  for (int k0 = 0; k0 < 1024; k0 += 32) {
    __syncthreads();  // previous iter's fragment reads done before overwrite
#pragma unroll
    for (int it = 0; it < 2; ++it) {
      const int c = w * 2 + it;  // chunk = 16 rows; wave-uniform LDS base
      gload_lds16(A + (size_t)(m0 + 16 * c + srow) * 1024 + k0 + scol,
                  &As[c * 512 + lane * 8]);
      gload_lds16(Bt + (size_t)(n0 + 16 * c + srow) * 1024 + k0 + scol,
                  &Bs[c * 512 + lane * 8]);
    }
    __syncthreads();  // barrier drain waits vmcnt(0): LDS tiles ready
    bf16x8 af[4], bfr[4];
#pragma unroll
    for (int i = 0; i < 4; ++i)
      af[i] = *reinterpret_cast<const bf16x8*>(&As[(wm + i * 16 + lr) * 32 + lk * 8]);
#pragma unroll
    for (int j = 0; j < 4; ++j)
      bfr[j] = *reinterpret_cast<const bf16x8*>(&Bs[(wn + j * 16 + lr) * 32 + lk * 8]);
#pragma unroll
    for (int i = 0; i < 4; ++i) {
#pragma unroll
      for (int j = 0; j < 4; ++j)
        acc[i][j] = MFMA_BF16(af[i], bfr[j], acc[i][j]);
    }
  }

#pragma unroll
  for (int i = 0; i < 4; ++i) {
#pragma unroll
    for (int j = 0; j < 4; ++j) {
#pragma unroll
      for (int r = 0; r < 4; ++r) {
        const int row = m0 + wm + i * 16 + lk * 4 + r;  // C/D: row=(lane>>4)*4+reg
        const int col = n0 + wn + j * 16 + lr;          //       col=lane&15
        const size_t idx = (size_t)row * 1024 + col;
        const float v = acc[i][j][r] + bias[col];
        if constexpr (EPI == 0) {
          Obf[(size_t)z * MD + idx] = f2bf(v);
        } else {
          Obf[idx] = f2bf(v + resid[idx]);
        }
      }
    }
  }
}

// ---------------- V head-transpose: Vt[bh][f][p'] bf16 ----------------
__global__ __launch_bounds__(256) void vt_k(const u16* __restrict__ VP,
                                            u16* __restrict__ VTo) {
  __shared__ __align__(16) u16 tile[64][72];
  const int t = threadIdx.x;
  const int bh = blockIdx.y, p0 = blockIdx.x * 64;
  const int b = bh >> 4, shi = bh & 15;
  const size_t hb = (size_t)b * 1048576 + (size_t)shi * 65536;
#pragma unroll
  for (int it = 0; it < 2; ++it) {
    const int c = t + it * 256;
    const int row = c >> 3, f8 = (c & 7) * 8;
    const int p = p0 + row;
    *reinterpret_cast<int4*>(&tile[row][f8]) = *reinterpret_cast<const int4*>(
        VP + hb + (size_t)(p >> 4) * 1024 + (p & 15) * 64 + f8);
  }
  __syncthreads();
#pragma unroll
  for (int it = 0; it < 2; ++it) {
    const int c = t + it * 256;
    const int f = c >> 3, pc = (c & 7) * 8;
    __align__(16) u16 tmp[8];
#pragma unroll
    for (int i = 0; i < 8; ++i) tmp[i] = tile[pc + i][f];
    *reinterpret_cast<int4*>(VTo + (size_t)bh * 65536 + (size_t)f * 1024 + p0 + pc) =
        *reinterpret_cast<int4*>(tmp);
  }
}

// ---------------- fused attention, single-pass, wave-specialized tail --------
// Grid (32, 128): qt = blockIdx.x FAST (L2 working set ~2 heads/XCD), bh = .y.
// 512 threads (8 waves), 2 blocks/CU. Block = 32 q-rows.
__global__ __launch_bounds__(512, 4) void attn_k(
    const u16* __restrict__ QP, const u16* __restrict__ KP,
    const u16* __restrict__ VT, const u64* __restrict__ mb,
    float* __restrict__ attnOut, u16* __restrict__ ctx) {
  __shared__ __align__(16) u16 Ps[32 * 1024];   // 64 KiB; swizzled
  __shared__ float red[8][2][16];

  const int t = threadIdx.x;
  const int qt = blockIdx.x;
  const int bh = blockIdx.y;
  const int q0 = qt * 32;
  const int b = bh >> 4, shi = bh & 15;
  const size_t hb = (size_t)b * 1048576 + (size_t)shi * 65536;
  const u64* mrow = mb + (size_t)(shi & 7) * 16384;  // [1024][16] words

  const int w = t >> 6, lane = t & 63, lr = lane & 15, lk = lane >> 4;
  const int qsw = (lr & 7) << 3;  // swizzle term (q-row low bits = lr&7)

  bf16x8 qf[2][2];
#pragma unroll
  for (int rg = 0; rg < 2; ++rg) {
    const u16* qb = QP + hb + (size_t)(qt * 2 + rg) * 1024 + lr * 64 + lk * 8;
    qf[rg][0] = *reinterpret_cast<const bf16x8*>(qb);
    qf[rg][1] = *reinterpret_cast<const bf16x8*>(qb + 32);
  }

  float psum[2] = {0.f, 0.f};

  // ---- phase 1: wave w handles kt = 2w, 2w+1 ----
#pragma unroll
  for (int ki = 0; ki < 2; ++ki) {
    const int kt = w * 2 + ki;
    const u16* kb = KP + hb + (size_t)(kt * 4) * 1024 + lr * 64 + lk * 8;
    bf16x8 kf[4][2];
#pragma unroll
    for (int j = 0; j < 4; ++j) {
      kf[j][0] = *reinterpret_cast<const bf16x8*>(kb + j * 1024);
      kf[j][1] = *reinterpret_cast<const bf16x8*>(kb + j * 1024 + 32);
    }
#pragma unroll
    for (int rg = 0; rg < 2; ++rg) {
      f32x4 sf[4];
#pragma unroll
      for (int j = 0; j < 4; ++j) {
        f32x4 a = {};
        a = MFMA_BF16(kf[j][0], qf[rg][0], a);
        a = MFMA_BF16(kf[j][1], qf[rg][1], a);
        sf[j] = a;  // S[k = kt*64+j*16+lk*4+r][q-row rg*16+lr]
      }
      const u64 mw = mrow[(size_t)(q0 + rg * 16 + lr) * 16 + kt];
#pragma unroll
      for (int j = 0; j < 4; ++j) {
        float p[4];
#pragma unroll
        for (int r = 0; r < 4; ++r) {
          const unsigned bit = (unsigned)(mw >> (j * 16 + lk * 4 + r)) & 1u;
          const float sel = bit ? -__builtin_inff() : 0.0f;
          p[r] = __builtin_amdgcn_exp2f(fmaf(sf[j][r], SCL, sel));
          psum[rg] += p[r];
        }
        const unsigned lo = cvt_pk_bf16(p[0], p[1]);
        const unsigned hi = cvt_pk_bf16(p[2], p[3]);
        const int kel = (kt * 64 + j * 16 + lk * 4) ^ qsw;
        *reinterpret_cast<u64*>(&Ps[(rg * 16 + lr) * 1024 + kel]) =
            (u64)lo | ((u64)hi << 32);
      }
    }
  }
#pragma unroll
  for (int rg = 0; rg < 2; ++rg) {
    psum[rg] += __shfl_xor(psum[rg], 16, 64);
    psum[rg] += __shfl_xor(psum[rg], 32, 64);
  }
  if (lane < 16) { red[w][0][lr] = psum[0]; red[w][1][lr] = psum[1]; }
  __syncthreads();

  // per-lane rinv for rows 0..31, shfl-broadcast
  float rsl = 0.f;
  if (lane < 32) {
#pragma unroll
    for (int w2 = 0; w2 < 8; ++w2) rsl += red[w2][lane >> 4][lane & 15];
  }
  const float rinvl = (rsl > 0.f) ? __builtin_amdgcn_rcpf(rsl) : 0.f;

  if (w < 4) {
    // ---- PV (waves 0-3): wave w -> ctx cols w*16..+15, both row groups ----
    const int cg = w * 16;
    const u16* vb = VT + (size_t)bh * 65536 + (size_t)(cg + lr) * 1024 + lk * 8;
    f32x4 cacc[2][2] = {};
#pragma unroll
    for (int kk = 0; kk < 32; ++kk) {
      const int kel = (kk * 32 + lk * 8) ^ qsw;
      const bf16x8 vf = *reinterpret_cast<const bf16x8*>(vb + kk * 32);
      const bf16x8 pf0 = *reinterpret_cast<const bf16x8*>(&Ps[lr * 1024 + kel]);
      const bf16x8 pf1 = *reinterpret_cast<const bf16x8*>(&Ps[(16 + lr) * 1024 + kel]);
      cacc[0][kk & 1] = MFMA_BF16(pf0, vf, cacc[0][kk & 1]);
      cacc[1][kk & 1] = MFMA_BF16(pf1, vf, cacc[1][kk & 1]);
    }
#pragma unroll
    for (int rg = 0; rg < 2; ++rg) {
#pragma unroll
      for (int r = 0; r < 4; ++r) {
        const int lrow = rg * 16 + lk * 4 + r;
        const float ri = __shfl(rinvl, lrow, 64);
        const float cv = cacc[rg][0][r] + cacc[rg][1][r];
        const int p = q0 + lrow;
        ctx[hb + (size_t)(p >> 4) * 1024 + (size_t)(p & 15) * 64 + cg + lr] =
            f2bf(cv * ri);
      }
    }
  } else {
    // ---- stores (waves 4-7): attnOut row i per iteration, 256 threads ----
    const int t2 = t - 256;
    float* aout = attnOut + (size_t)bh * 1048576 + (size_t)q0 * 1024;
#pragma unroll
    for (int i = 0; i < 32; ++i) {
      const int asw = (i & 7) << 3;
      const float ri = __shfl(rinvl, i, 64);
      const u64 p4 = *reinterpret_cast<const u64*>(&Ps[i * 1024 + ((t2 * 4) ^ asw)]);
      f32x4 o;
      o[0] = bf2f((u16)(p4 & 0xffffu)) * ri;
      o[1] = bf2f((u16)((p4 >> 16) & 0xffffu)) * ri;
      o[2] = bf2f((u16)((p4 >> 32) & 0xffffu)) * ri;
      o[3] = bf2f((u16)(p4 >> 48)) * ri;
      __builtin_nontemporal_store(
          o, reinterpret_cast<f32x4*>(aout + (size_t)i * 1024 + t2 * 4));
    }
  }
}

// ---------------- LayerNorm over last dim (1024), bf16 input ----------------
__global__ __launch_bounds__(256) void ln_k(const u16* __restrict__ X,
                                            const float* __restrict__ gamma,
                                            const float* __restrict__ beta,
                                            float* __restrict__ Y) {
  const int row = blockIdx.x, t = threadIdx.x;
  const size_t base = (size_t)row * 1024;
  const u64 xw = *reinterpret_cast<const u64*>(X + base + t * 4);
  float x0 = bf2f((u16)(xw & 0xffffu));
  float x1 = bf2f((u16)((xw >> 16) & 0xffffu));
  float x2 = bf2f((u16)((xw >> 32) & 0xffffu));
  float x3 = bf2f((u16)(xw >> 48));
  float s = x0 + x1 + x2 + x3;
  float s2 = x0 * x0 + x1 * x1 + x2 * x2 + x3 * x3;
#pragma unroll
  for (int d = 1; d < 64; d <<= 1) {
    s += __shfl_xor(s, d, 64);
    s2 += __shfl_xor(s2, d, 64);
  }
  __shared__ float red[8];
  const int w = t >> 6;
  if ((t & 63) == 0) { red[w] = s; red[4 + w] = s2; }
  __syncthreads();
  s = red[0] + red[1] + red[2] + red[3];
  s2 = red[4] + red[5] + red[6] + red[7];
  const float mu = s * (1.f / 1024.f);
  const float var = s2 * (1.f / 1024.f) - mu * mu;
  const float inv = rsqrtf(var + 1e-5f);
  const float4 g = *reinterpret_cast<const float4*>(gamma + t * 4);
  const float4 be = *reinterpret_cast<const float4*>(beta + t * 4);
  float4 y;
  y.x = (x0 - mu) * inv * g.x + be.x;
  y.y = (x1 - mu) * inv * g.y + be.y;
  y.z = (x2 - mu) * inv * g.z + be.z;
  y.w = (x3 - mu) * inv * g.w + be.w;
  *reinterpret_cast<float4*>(Y + base + t * 4) = y;
}

extern "C" void kernel_launch(void* const* d_in, const int* in_sizes, int n_in,
                              void* d_out, int out_size, void* d_ws, size_t ws_size,
                              hipStream_t stream) {
  const float* keyF = (const float*)d_in[0];
  const float* valueF = (const float*)d_in[1];
  const float* queryF = (const float*)d_in[2];
  const unsigned char* mask8 = (const unsigned char*)d_in[3];
  const float* Wk = (const float*)d_in[4];
  const float* bk = (const float*)d_in[5];
  const float* Wv = (const float*)d_in[6];
  const float* bv = (const float*)d_in[7];
  const float* Wq = (const float*)d_in[8];
  const float* bq = (const float*)d_in[9];
  const float* Wf = (const float*)d_in[10];
  const float* bfp = (const float*)d_in[11];
  const float* gamma = (const float*)d_in[12];
  const float* beta = (const float*)d_in[13];

  char* ws = (char*)d_ws;
  // layout (bytes): [0,48M) Xbf k/v/q bf16 | [48M,56M) WT x4 | [56M,104M) K/V/Q proj
  // | [104M,120M) Vt | [120M,121M) mask bits. After projections: [0,16M) ctx,
  // [16M,32M) preLN bf16 (overwrites Xbf region after its last use).
  u16* Xbf = (u16*)(ws);
  u16* WT = (u16*)(ws + 50331648);
  u16* KP = (u16*)(ws + 58720256);
  u16* VP = (u16*)(ws + 75497472);
  u16* QP = (u16*)(ws + 92274688);
  u16* VT = (u16*)(ws + 109051904);
  u64* MB = (u64*)(ws + 125829120);
  u16* CTX = (u16*)(ws);
  u16* PRELN = (u16*)(ws + 16777216);

  float* outF = (float*)d_out;
  float* attnF = outF + 8388608;

  prep_k<<<dim3(29696), 256, 0, stream>>>(keyF, valueF, queryF, Wk, Wv, Wq, Wf,
                                          mask8, Xbf, WT, MB);
  gemm_bt<0><<<dim3(8, 64, 3), 256, 0, stream>>>(Xbf, WT, bk, bv, bq, KP, nullptr);
  vt_k<<<dim3(16, 128), 256, 0, stream>>>(VP, VT);
  attn_k<<<dim3(32, 128), 512, 0, stream>>>(QP, KP, VT, MB, attnF, CTX);
  gemm_bt<1><<<dim3(8, 64, 1), 256, 0, stream>>>(CTX, WT + 3 * DD, bfp, bfp, bfp,
                                                 PRELN, queryF);
  ln_k<<<dim3(8192), 256, 0, stream>>>(PRELN, gamma, beta, outF);
}

// Round 13
// 320.973 us; speedup vs baseline: 1.1260x; 1.0020x over previous
//
#include <hip/hip_runtime.h>

// B=8 S=1024 D=1024 H=16 DH=64.
// Head bh=b*16+s_hi (s_hi=s>>6); head elem (p,f) -> proj[b][s_hi*64+(p>>4)][(p&15)*64+f].
// mask index for head bh is s_hi&7. scale=0.5 (=> exp2 domain: 0.5*log2e).

typedef unsigned short u16;
typedef unsigned long long u64;
typedef __attribute__((ext_vector_type(8))) short bf16x8;
typedef __attribute__((ext_vector_type(4))) float f32x4;

#define MFMA_BF16(a, b, c) __builtin_amdgcn_mfma_f32_16x16x32_bf16((a), (b), (c), 0, 0, 0)

__device__ __forceinline__ u16 f2bf(float f) {
  unsigned u = __float_as_uint(f);
  u += 0x7fffu + ((u >> 16) & 1u);   // round-nearest-even
  return (u16)(u >> 16);
}
__device__ __forceinline__ float bf2f(u16 b) {
  return __uint_as_float(((unsigned)b) << 16);
}
__device__ __forceinline__ unsigned cvt_pk_bf16(float lo, float hi) {
  unsigned r;
  asm("v_cvt_pk_bf16_f32 %0, %1, %2" : "=v"(r) : "v"(lo), "v"(hi));
  return r;
}
__device__ __forceinline__ void gload_lds16(const u16* g, u16* l) {
  __builtin_amdgcn_global_load_lds(
      (const __attribute__((address_space(1))) void*)g,
      (__attribute__((address_space(3))) void*)l, 16, 0, 0);
}

static constexpr size_t MD = 8192ull * 1024ull;  // one [B,S,D] tensor, elements
static constexpr size_t DD = 1024ull * 1024ull;  // one [D,D] weight, elements
static constexpr float SCL = 0.72134752044f;     // 0.5 * log2(e)

// ------- fused f32->bf16 cvt (ids 0..24575) + W-transpose (..28671) + mask ----
// 1D grid, 29696 blocks.
__global__ __launch_bounds__(256) void prep_k(
    const float* __restrict__ K, const float* __restrict__ V,
    const float* __restrict__ Q, const float* __restrict__ Wk,
    const float* __restrict__ Wv, const float* __restrict__ Wq,
    const float* __restrict__ Wf, const unsigned char* __restrict__ mask8,
    u16* __restrict__ O, u16* __restrict__ WT, u64* __restrict__ mb) {
  const int id = blockIdx.x;
  const int t = threadIdx.x;
  if (id < 24576) {  // ---- cvt: 3 x 8192 blocks ----
    const int z = id >> 13, x = id & 8191;
    const float* src = (z == 0) ? K : ((z == 1) ? V : Q);
    const size_t i = ((size_t)x * 256 + t) * 4;
    const float4 v = *reinterpret_cast<const float4*>(src + i);
    const unsigned lo = cvt_pk_bf16(v.x, v.y);
    const unsigned hi = cvt_pk_bf16(v.z, v.w);
    *reinterpret_cast<u64*>(O + (size_t)z * MD + i) = (u64)lo | ((u64)hi << 32);
    return;
  }
  if (id < 28672) {  // ---- W transpose: 4 x 1024 blocks (32x32 tiles) ----
    __shared__ float tile[32][33];
    const int id2 = id - 24576;
    const int z = id2 >> 10, y = (id2 & 1023) >> 5, x = id2 & 31;
    const float* W = (z == 0) ? Wk : ((z == 1) ? Wv : ((z == 2) ? Wq : Wf));
    const int k0 = y * 32, n0 = x * 32;
    const int r = t >> 5, c = t & 31;
#pragma unroll
    for (int rr = r; rr < 32; rr += 8)
      tile[rr][c] = W[(size_t)(k0 + rr) * 1024 + n0 + c];
    __syncthreads();
#pragma unroll
    for (int rr = r; rr < 32; rr += 8)
      WT[(size_t)z * DD + (size_t)(n0 + rr) * 1024 + k0 + c] = f2bf(tile[c][rr]);
    return;
  }
  // ---- mask bitpack: 1024 blocks x 128 words (threads 0..127) ----
  __shared__ int mflag;
  if (t == 0) {
    const unsigned* mw = reinterpret_cast<const unsigned*>(mask8);
    int allW = 1;  // storage is 4-byte words (int32 0/1 or f32 0.0/1.0)?
    for (int i = 0; i < 64; ++i) {
      const unsigned v = mw[i];
      if (v != 0u && v != 1u && v != 0x3F800000u) allW = 0;
    }
    mflag = allW;
  }
  __syncthreads();
  if (t >= 128) return;
  const int wide = mflag;
  const size_t wi = (size_t)(id - 28672) * 128 + t;  // word idx, 131072 total
  const size_t src0 = wi * 64;
  u64 bits = 0ull;
  if (!wide) {  // u8 bool storage
    const uint4* p = reinterpret_cast<const uint4*>(mask8 + src0);
#pragma unroll
    for (int q = 0; q < 4; ++q) {
      const uint4 v = p[q];
      const unsigned vv[4] = {v.x, v.y, v.z, v.w};
#pragma unroll
      for (int k = 0; k < 4; ++k) {
        unsigned tt = vv[k];
        tt |= tt >> 4; tt |= tt >> 2; tt |= tt >> 1;
        tt &= 0x01010101u;
        const unsigned nib =
            (tt & 1u) | ((tt >> 7) & 2u) | ((tt >> 14) & 4u) | ((tt >> 21) & 8u);
        bits |= (u64)nib << (q * 16 + k * 4);
      }
    }
  } else {  // 4-byte storage: nonzero word => masked
    const unsigned* p = reinterpret_cast<const unsigned*>(mask8) + src0;
#pragma unroll
    for (int k = 0; k < 64; ++k)
      bits |= (u64)(p[k] != 0u) << k;
  }
  mb[wi] = bits;
}

// ---------------- GEMM (m97 pattern): C = A * BT^T (+bias, epilogues) -------
// Linear LDS [128][32], global_load_lds width-16, ds_read_b128 fragments.
// XCD-chunk swizzle: consecutive logical blocks (same m-row panel, all n) land
// on ONE XCD -> A panels L2-resident.
// EPI==0: C -> bf16 (projections, z=0,1,2). EPI==1: C+resid(bf16) -> bf16.
template <int EPI>
__global__ __launch_bounds__(256) void gemm_bt(
    const u16* __restrict__ A0, const u16* __restrict__ B0,
    const float* __restrict__ bias0, const float* __restrict__ bias1,
    const float* __restrict__ bias2, u16* __restrict__ Obf,
    const u16* __restrict__ residbf) {
  __shared__ __align__(16) u16 As[128 * 32];  // 64B per row, linear (gload_lds dest)
  __shared__ __align__(16) u16 Bs[128 * 32];
  // bijective XCD swizzle (nwg % 8 == 0): wg = (flat%8)*cpx + flat/8
  const int nxy = gridDim.x * gridDim.y;
  const int nwg = nxy * gridDim.z;
  const int flat = blockIdx.z * nxy + blockIdx.y * gridDim.x + blockIdx.x;
  const int wg = (flat & 7) * (nwg >> 3) + (flat >> 3);
  const int z = wg / nxy;
  const int rem = wg - z * nxy;
  const int m0 = (rem >> 3) * 128, n0 = (rem & 7) * 128;

  const u16* A = A0 + (size_t)z * MD;
  const u16* Bt = B0 + (size_t)z * DD;
  const float* bias = (z == 0) ? bias0 : ((z == 1) ? bias1 : bias2);
  const int t = threadIdx.x;
  const int w = t >> 6, lane = t & 63, lr = lane & 15, lk = lane >> 4;
  const int wm = (w >> 1) * 64, wn = (w & 1) * 64;
  const int srow = lane >> 2, scol = (lane & 3) * 8;  // within 16-row chunk

  f32x4 acc[4][4] = {};

  for (int k0 = 0; k0 < 1024; k0 += 32) {
    __syncthreads();  // previous iter's fragment reads done before overwrite
#pragma unroll
    for (int it = 0; it < 2; ++it) {
      const int c = w * 2 + it;  // chunk = 16 rows; wave-uniform LDS base
      gload_lds16(A + (size_t)(m0 + 16 * c + srow) * 1024 + k0 + scol,
                  &As[c * 512 + lane * 8]);
      gload_lds16(Bt + (size_t)(n0 + 16 * c + srow) * 1024 + k0 + scol,
                  &Bs[c * 512 + lane * 8]);
    }
    __syncthreads();  // barrier drain waits vmcnt(0): LDS tiles ready
    bf16x8 af[4], bfr[4];
#pragma unroll
    for (int i = 0; i < 4; ++i)
      af[i] = *reinterpret_cast<const bf16x8*>(&As[(wm + i * 16 + lr) * 32 + lk * 8]);
#pragma unroll
    for (int j = 0; j < 4; ++j)
      bfr[j] = *reinterpret_cast<const bf16x8*>(&Bs[(wn + j * 16 + lr) * 32 + lk * 8]);
#pragma unroll
    for (int i = 0; i < 4; ++i) {
#pragma unroll
      for (int j = 0; j < 4; ++j)
        acc[i][j] = MFMA_BF16(af[i], bfr[j], acc[i][j]);
    }
  }

#pragma unroll
  for (int i = 0; i < 4; ++i) {
#pragma unroll
    for (int j = 0; j < 4; ++j) {
#pragma unroll
      for (int r = 0; r < 4; ++r) {
        const int row = m0 + wm + i * 16 + lk * 4 + r;  // C/D: row=(lane>>4)*4+reg
        const int col = n0 + wn + j * 16 + lr;          //       col=lane&15
        const size_t idx = (size_t)row * 1024 + col;
        const float v = acc[i][j][r] + bias[col];
        if constexpr (EPI == 0) {
          Obf[(size_t)z * MD + idx] = f2bf(v);
        } else {
          Obf[idx] = f2bf(v + bf2f(residbf[idx]));
        }
      }
    }
  }
}

// ---------------- V head-transpose: Vt[bh][f][p'] bf16 ----------------
__global__ __launch_bounds__(256) void vt_k(const u16* __restrict__ VP,
                                            u16* __restrict__ VTo) {
  __shared__ __align__(16) u16 tile[64][72];
  const int t = threadIdx.x;
  const int bh = blockIdx.y, p0 = blockIdx.x * 64;
  const int b = bh >> 4, shi = bh & 15;
  const size_t hb = (size_t)b * 1048576 + (size_t)shi * 65536;
#pragma unroll
  for (int it = 0; it < 2; ++it) {
    const int c = t + it * 256;
    const int row = c >> 3, f8 = (c & 7) * 8;
    const int p = p0 + row;
    *reinterpret_cast<int4*>(&tile[row][f8]) = *reinterpret_cast<const int4*>(
        VP + hb + (size_t)(p >> 4) * 1024 + (p & 15) * 64 + f8);
  }
  __syncthreads();
#pragma unroll
  for (int it = 0; it < 2; ++it) {
    const int c = t + it * 256;
    const int f = c >> 3, pc = (c & 7) * 8;
    __align__(16) u16 tmp[8];
#pragma unroll
    for (int i = 0; i < 8; ++i) tmp[i] = tile[pc + i][f];
    *reinterpret_cast<int4*>(VTo + (size_t)bh * 65536 + (size_t)f * 1024 + p0 + pc) =
        *reinterpret_cast<int4*>(tmp);
  }
}

// ---------------- fused attention, single-pass, wave-specialized tail --------
// Grid (32, 128): qt = blockIdx.x FAST (L2 working set ~2 heads/XCD), bh = .y.
// 512 threads (8 waves), 2 blocks/CU. Block = 32 q-rows. (R11 version, verified.)
__global__ __launch_bounds__(512, 4) void attn_k(
    const u16* __restrict__ QP, const u16* __restrict__ KP,
    const u16* __restrict__ VT, const u64* __restrict__ mb,
    float* __restrict__ attnOut, u16* __restrict__ ctx) {
  __shared__ __align__(16) u16 Ps[32 * 1024];   // 64 KiB; swizzled
  __shared__ float red[8][2][16];

  const int t = threadIdx.x;
  const int qt = blockIdx.x;
  const int bh = blockIdx.y;
  const int q0 = qt * 32;
  const int b = bh >> 4, shi = bh & 15;
  const size_t hb = (size_t)b * 1048576 + (size_t)shi * 65536;
  const u64* mrow = mb + (size_t)(shi & 7) * 16384;  // [1024][16] words

  const int w = t >> 6, lane = t & 63, lr = lane & 15, lk = lane >> 4;
  const int qsw = (lr & 7) << 3;  // swizzle term (q-row low bits = lr&7)

  bf16x8 qf[2][2];
#pragma unroll
  for (int rg = 0; rg < 2; ++rg) {
    const u16* qb = QP + hb + (size_t)(qt * 2 + rg) * 1024 + lr * 64 + lk * 8;
    qf[rg][0] = *reinterpret_cast<const bf16x8*>(qb);
    qf[rg][1] = *reinterpret_cast<const bf16x8*>(qb + 32);
  }

  float psum[2] = {0.f, 0.f};

  // ---- phase 1: wave w handles kt = 2w, 2w+1 ----
#pragma unroll
  for (int ki = 0; ki < 2; ++ki) {
    const int kt = w * 2 + ki;
    const u16* kb = KP + hb + (size_t)(kt * 4) * 1024 + lr * 64 + lk * 8;
    bf16x8 kf[4][2];
#pragma unroll
    for (int j = 0; j < 4; ++j) {
      kf[j][0] = *reinterpret_cast<const bf16x8*>(kb + j * 1024);
      kf[j][1] = *reinterpret_cast<const bf16x8*>(kb + j * 1024 + 32);
    }
#pragma unroll
    for (int rg = 0; rg < 2; ++rg) {
      f32x4 sf[4];
#pragma unroll
      for (int j = 0; j < 4; ++j) {
        f32x4 a = {};
        a = MFMA_BF16(kf[j][0], qf[rg][0], a);
        a = MFMA_BF16(kf[j][1], qf[rg][1], a);
        sf[j] = a;  // S[k = kt*64+j*16+lk*4+r][q-row rg*16+lr]
      }
      const u64 mw = mrow[(size_t)(q0 + rg * 16 + lr) * 16 + kt];
#pragma unroll
      for (int j = 0; j < 4; ++j) {
        float p[4];
#pragma unroll
        for (int r = 0; r < 4; ++r) {
          const unsigned bit = (unsigned)(mw >> (j * 16 + lk * 4 + r)) & 1u;
          const float sel = bit ? -__builtin_inff() : 0.0f;
          p[r] = __builtin_amdgcn_exp2f(fmaf(sf[j][r], SCL, sel));
          psum[rg] += p[r];
        }
        const unsigned lo = cvt_pk_bf16(p[0], p[1]);
        const unsigned hi = cvt_pk_bf16(p[2], p[3]);
        const int kel = (kt * 64 + j * 16 + lk * 4) ^ qsw;
        *reinterpret_cast<u64*>(&Ps[(rg * 16 + lr) * 1024 + kel]) =
            (u64)lo | ((u64)hi << 32);
      }
    }
  }
#pragma unroll
  for (int rg = 0; rg < 2; ++rg) {
    psum[rg] += __shfl_xor(psum[rg], 16, 64);
    psum[rg] += __shfl_xor(psum[rg], 32, 64);
  }
  if (lane < 16) { red[w][0][lr] = psum[0]; red[w][1][lr] = psum[1]; }
  __syncthreads();

  // per-lane rinv for rows 0..31, shfl-broadcast
  float rsl = 0.f;
  if (lane < 32) {
#pragma unroll
    for (int w2 = 0; w2 < 8; ++w2) rsl += red[w2][lane >> 4][lane & 15];
  }
  const float rinvl = (rsl > 0.f) ? __builtin_amdgcn_rcpf(rsl) : 0.f;

  if (w < 4) {
    // ---- PV (waves 0-3): wave w -> ctx cols w*16..+15, both row groups ----
    const int cg = w * 16;
    const u16* vb = VT + (size_t)bh * 65536 + (size_t)(cg + lr) * 1024 + lk * 8;
    f32x4 cacc[2][2] = {};
#pragma unroll
    for (int kk = 0; kk < 32; ++kk) {
      const int kel = (kk * 32 + lk * 8) ^ qsw;
      const bf16x8 vf = *reinterpret_cast<const bf16x8*>(vb + kk * 32);
      const bf16x8 pf0 = *reinterpret_cast<const bf16x8*>(&Ps[lr * 1024 + kel]);
      const bf16x8 pf1 = *reinterpret_cast<const bf16x8*>(&Ps[(16 + lr) * 1024 + kel]);
      cacc[0][kk & 1] = MFMA_BF16(pf0, vf, cacc[0][kk & 1]);
      cacc[1][kk & 1] = MFMA_BF16(pf1, vf, cacc[1][kk & 1]);
    }
#pragma unroll
    for (int rg = 0; rg < 2; ++rg) {
#pragma unroll
      for (int r = 0; r < 4; ++r) {
        const int lrow = rg * 16 + lk * 4 + r;
        const float ri = __shfl(rinvl, lrow, 64);
        const float cv = cacc[rg][0][r] + cacc[rg][1][r];
        const int p = q0 + lrow;
        ctx[hb + (size_t)(p >> 4) * 1024 + (size_t)(p & 15) * 64 + cg + lr] =
            f2bf(cv * ri);
      }
    }
  } else {
    // ---- stores (waves 4-7): attnOut row i per iteration, 256 threads ----
    const int t2 = t - 256;
    float* aout = attnOut + (size_t)bh * 1048576 + (size_t)q0 * 1024;
#pragma unroll
    for (int i = 0; i < 32; ++i) {
      const int asw = (i & 7) << 3;
      const float ri = __shfl(rinvl, i, 64);
      const u64 p4 = *reinterpret_cast<const u64*>(&Ps[i * 1024 + ((t2 * 4) ^ asw)]);
      f32x4 o;
      o[0] = bf2f((u16)(p4 & 0xffffu)) * ri;
      o[1] = bf2f((u16)((p4 >> 16) & 0xffffu)) * ri;
      o[2] = bf2f((u16)((p4 >> 32) & 0xffffu)) * ri;
      o[3] = bf2f((u16)(p4 >> 48)) * ri;
      __builtin_nontemporal_store(
          o, reinterpret_cast<f32x4*>(aout + (size_t)i * 1024 + t2 * 4));
    }
  }
}

// ---------------- LayerNorm over last dim (1024), bf16 input ----------------
__global__ __launch_bounds__(256) void ln_k(const u16* __restrict__ X,
                                            const float* __restrict__ gamma,
                                            const float* __restrict__ beta,
                                            float* __restrict__ Y) {
  const int row = blockIdx.x, t = threadIdx.x;
  const size_t base = (size_t)row * 1024;
  const u64 xw = *reinterpret_cast<const u64*>(X + base + t * 4);
  float x0 = bf2f((u16)(xw & 0xffffu));
  float x1 = bf2f((u16)((xw >> 16) & 0xffffu));
  float x2 = bf2f((u16)((xw >> 32) & 0xffffu));
  float x3 = bf2f((u16)(xw >> 48));
  float s = x0 + x1 + x2 + x3;
  float s2 = x0 * x0 + x1 * x1 + x2 * x2 + x3 * x3;
#pragma unroll
  for (int d = 1; d < 64; d <<= 1) {
    s += __shfl_xor(s, d, 64);
    s2 += __shfl_xor(s2, d, 64);
  }
  __shared__ float red[8];
  const int w = t >> 6;
  if ((t & 63) == 0) { red[w] = s; red[4 + w] = s2; }
  __syncthreads();
  s = red[0] + red[1] + red[2] + red[3];
  s2 = red[4] + red[5] + red[6] + red[7];
  const float mu = s * (1.f / 1024.f);
  const float var = s2 * (1.f / 1024.f) - mu * mu;
  const float inv = rsqrtf(var + 1e-5f);
  const float4 g = *reinterpret_cast<const float4*>(gamma + t * 4);
  const float4 be = *reinterpret_cast<const float4*>(beta + t * 4);
  float4 y;
  y.x = (x0 - mu) * inv * g.x + be.x;
  y.y = (x1 - mu) * inv * g.y + be.y;
  y.z = (x2 - mu) * inv * g.z + be.z;
  y.w = (x3 - mu) * inv * g.w + be.w;
  *reinterpret_cast<float4*>(Y + base + t * 4) = y;
}

extern "C" void kernel_launch(void* const* d_in, const int* in_sizes, int n_in,
                              void* d_out, int out_size, void* d_ws, size_t ws_size,
                              hipStream_t stream) {
  const float* keyF = (const float*)d_in[0];
  const float* valueF = (const float*)d_in[1];
  const float* queryF = (const float*)d_in[2];
  const unsigned char* mask8 = (const unsigned char*)d_in[3];
  const float* Wk = (const float*)d_in[4];
  const float* bk = (const float*)d_in[5];
  const float* Wv = (const float*)d_in[6];
  const float* bv = (const float*)d_in[7];
  const float* Wq = (const float*)d_in[8];
  const float* bq = (const float*)d_in[9];
  const float* Wf = (const float*)d_in[10];
  const float* bfp = (const float*)d_in[11];
  const float* gamma = (const float*)d_in[12];
  const float* beta = (const float*)d_in[13];

  char* ws = (char*)d_ws;
  // layout (bytes): [0,48M) Xbf k/v/q bf16 | [48M,56M) WT x4 | [56M,104M) K/V/Q proj
  // | [104M,120M) Vt | [120M,121M) mask bits. After projections: [0,16M) ctx
  // (over K's Xbf), [16M,32M) preLN bf16 (over V's Xbf); Q's Xbf [32M,48M) stays
  // live as the bf16 residual for gemm_bt<1>.
  u16* Xbf = (u16*)(ws);
  u16* WT = (u16*)(ws + 50331648);
  u16* KP = (u16*)(ws + 58720256);
  u16* VP = (u16*)(ws + 75497472);
  u16* QP = (u16*)(ws + 92274688);
  u16* VT = (u16*)(ws + 109051904);
  u64* MB = (u64*)(ws + 125829120);
  u16* CTX = (u16*)(ws);
  u16* PRELN = (u16*)(ws + 16777216);
  u16* QRES = (u16*)(ws + 33554432);  // Xbf z=2 (query bf16)

  float* outF = (float*)d_out;
  float* attnF = outF + 8388608;

  prep_k<<<dim3(29696), 256, 0, stream>>>(keyF, valueF, queryF, Wk, Wv, Wq, Wf,
                                          mask8, Xbf, WT, MB);
  gemm_bt<0><<<dim3(8, 64, 3), 256, 0, stream>>>(Xbf, WT, bk, bv, bq, KP, nullptr);
  vt_k<<<dim3(16, 128), 256, 0, stream>>>(VP, VT);
  attn_k<<<dim3(32, 128), 512, 0, stream>>>(QP, KP, VT, MB, attnF, CTX);
  gemm_bt<1><<<dim3(8, 64, 1), 256, 0, stream>>>(CTX, WT + 3 * DD, bfp, bfp, bfp,
                                                 PRELN, QRES);
  ln_k<<<dim3(8192), 256, 0, stream>>>(PRELN, gamma, beta, outF);
}